// Round 9
// baseline (313.080 us; speedup 1.0000x reference)
//
#include <hip/hip_runtime.h>
#include <hip/hip_bf16.h>

typedef __bf16 bf16x8 __attribute__((ext_vector_type(8)));
typedef float f32x4 __attribute__((ext_vector_type(4)));
typedef short s16x8 __attribute__((ext_vector_type(8)));
typedef short s16x4 __attribute__((ext_vector_type(4)));

#define NTOK 49
#define CDIM 96
#define KS_S 104   // Ks row stride (ushort), 208B
#define VT_S 56    // V'^T row stride (ushort), 112B
#define BN_S 192   // bounce row stride (ushort), 384B: Q@0..95, P0@0..63*, P1@64..127, P2@128..191
#define LOG2E 1.4426950408889634f

#if __has_builtin(__builtin_amdgcn_exp2f)
#define EXP2F(x) __builtin_amdgcn_exp2f(x)
#else
#define EXP2F(x) exp2f(x)
#endif

#define DRAIN() do { asm volatile("s_waitcnt lgkmcnt(0)" ::: "memory"); \
                     __builtin_amdgcn_sched_barrier(0); } while (0)

__device__ __forceinline__ unsigned short f2bf(float f) {
  __hip_bfloat16 h = __float2bfloat16(f);
  return __builtin_bit_cast(unsigned short, h);
}
__device__ __forceinline__ unsigned int cvtpk(float lo, float hi) {
  unsigned int r;
  asm("v_cvt_pk_bf16_f32 %0, %1, %2" : "=v"(r) : "v"(lo), "v"(hi));
  return r;
}
__device__ __forceinline__ unsigned short f2bf_f(float f) {
  return (unsigned short)cvtpk(f, f);
}
__device__ __forceinline__ s16x4 pack4(float a, float b, float c, float d) {
  union { unsigned int u[2]; s16x4 v; } r;
  r.u[0] = cvtpk(a, b); r.u[1] = cvtpk(c, d);
  return r.v;
}
__device__ __forceinline__ bf16x8 ld_cvt8(const float* p) {
  float4 a = *(const float4*)p;
  float4 b = *(const float4*)(p + 4);
  union { unsigned int u[4]; bf16x8 v; } r;
  r.u[0] = cvtpk(a.x, a.y); r.u[1] = cvtpk(a.z, a.w);
  r.u[2] = cvtpk(b.x, b.y); r.u[3] = cvtpk(b.z, b.w);
  return r.v;
}

// d_ws layout:
//   ushort[0     ..  9216)  wqT  [oc 96][ic 96]        (bf16 bits)
//   ushort[9216  .. 18432)  wkT  [oc 96][ic 96]        (K half of wkv)
//   ushort[18432 .. 46080)  W2T  [h 3][oc 96][ic 96]   (Wkv_v @ Wproj_h, f32 math -> bf16)
//   byte 92160:  float biasf[3][49][64]   (rpb * log2e, cols 49..63 = 0)
//   byte 129792: float btot[96]           (bproj + bkv_v @ Wproj; P rows sum to 1)
__global__ void prep(const float* __restrict__ wq, const float* __restrict__ wkv,
                     const float* __restrict__ wproj, const float* __restrict__ rpb,
                     const int* __restrict__ relidx, const float* __restrict__ bkv,
                     const float* __restrict__ bproj,
                     unsigned short* __restrict__ wsT, float* __restrict__ biasf,
                     float* __restrict__ btot) {
  const int total = 46080 + 3 * 49 * 64 + 96;
  for (int i = blockIdx.x * 256 + threadIdx.x; i < total; i += gridDim.x * 256) {
    if (i < 9216) {
      int oc = i / 96, ic = i - oc * 96;
      wsT[i] = f2bf(wq[ic * 96 + oc]);
    } else if (i < 18432) {
      int j = i - 9216; int oc = j / 96, ic = j - oc * 96;
      wsT[i] = f2bf(wkv[ic * 192 + oc]);                  // K half (cols 0..95)
    } else if (i < 46080) {
      int j = i - 18432; int h = j / 9216; int rem = j - h * 9216;
      int oc = rem / 96, ic = rem - oc * 96;
      float s = 0.f;
      for (int d = 0; d < 32; ++d)
        s += wkv[ic * 192 + 96 + h * 32 + d] * wproj[(h * 32 + d) * 96 + oc];
      wsT[i] = f2bf(s);
    } else if (i < 46080 + 9408) {
      int j = i - 46080; int h = j / 3136; int rc = j - h * 3136;
      int r = rc >> 6, c = rc & 63;
      biasf[j] = (c < 49) ? rpb[relidx[r * 49 + c] * 3 + h] * LOG2E : 0.f;
    } else {
      int oc = i - (46080 + 9408);
      float s = bproj[oc];
      for (int j = 0; j < 96; ++j) s += bkv[96 + j] * wproj[j * 96 + oc];
      btot[oc] = s;
    }
  }
}

// One block = one window, 4 waves (token tiles {0,16,32,33}), ONE barrier,
// ONE counted drain in the tail. Wproj folded into V' = v @ W2 (prep), so the
// post-softmax tail is: P bounce -> DRAIN -> 36 independent PV' MFMAs -> store.
__launch_bounds__(256, 2)
__global__ void attn_fused(const float* __restrict__ xg, const float* __restrict__ vg,
                           const float* __restrict__ bq, const float* __restrict__ bkv,
                           const unsigned short* __restrict__ wsT,
                           const float* __restrict__ biasf,
                           const float* __restrict__ btot,
                           float* __restrict__ outg) {
  // LDS (bytes): [0,10192) Ks[49][104] (rows 49..63 bleed-read -> masked in softmax)
  //              [10192,42448) VPT[288][56]  (V'^T[h*96+oc][key]; keys 49.. -> vmask)
  //              [42448,67024) bounce[4 waves][16][192]
  __shared__ __align__(16) unsigned char smem[67024];
  unsigned short* Ks  = (unsigned short*)smem;
  unsigned short* VPT = (unsigned short*)(smem + 10192);

  const int tid = threadIdx.x, lane = tid & 63, wv = tid >> 6;
  const int c16 = lane & 15, g4 = lane >> 4;
  const int win = blockIdx.x;
  const int q0 = (wv == 0) ? 0 : (wv == 1) ? 16 : (wv == 2) ? 32 : 33;
  unsigned short* bnc = (unsigned short*)(smem + 42448) + wv * (16 * BN_S);

  const float* xrow = xg + (size_t)win * (NTOK * CDIM) + (q0 + c16) * CDIM;
  const float* vrow = vg + (size_t)win * (NTOK * CDIM) + (q0 + c16) * CDIM;

  // ---- own token tile: x, v fragments direct from global ----
  bf16x8 xf[3], vf[3];
#pragma unroll
  for (int k = 0; k < 3; ++k) {
    xf[k] = ld_cvt8(xrow + k * 32 + g4 * 8);
    vf[k] = ld_cvt8(vrow + k * 32 + g4 * 8);
  }
  // biases hoisted
  float bqv[6], bkvv[6];
#pragma unroll
  for (int nt = 0; nt < 6; ++nt) {
    bqv[nt]  = bq[nt * 16 + c16];
    bkvv[nt] = bkv[nt * 16 + c16];
  }

  // ---- V' projection: V'^T[h][oc][key] for own token tile (2 passes x 9 tiles) ----
#pragma unroll
  for (int pass = 0; pass < 2; ++pass) {
    f32x4 acc[9] = {{0,0,0,0},{0,0,0,0},{0,0,0,0},{0,0,0,0},{0,0,0,0},
                    {0,0,0,0},{0,0,0,0},{0,0,0,0},{0,0,0,0}};
#pragma unroll
    for (int kf = 0; kf < 3; ++kf) {
      bf16x8 wf[9];
#pragma unroll
      for (int u9 = 0; u9 < 9; ++u9) {
        int u = pass * 9 + u9;
        int h = u / 6, oct = u - h * 6;
        wf[u9] = *(const bf16x8*)(wsT + 18432 + h * 9216 +
                                  (oct * 16 + c16) * 96 + kf * 32 + g4 * 8);
      }
      __builtin_amdgcn_s_setprio(1);
#pragma unroll
      for (int u9 = 0; u9 < 9; ++u9)
        acc[u9] = __builtin_amdgcn_mfma_f32_16x16x32_bf16(vf[kf], wf[u9], acc[u9], 0, 0, 0);
      __builtin_amdgcn_s_setprio(0);
    }
#pragma unroll
    for (int u9 = 0; u9 < 9; ++u9) {
      int u = pass * 9 + u9;
      int h = u / 6, oct = u - h * 6;
      unsigned short* row = VPT + (h * 96 + oct * 16 + c16) * VT_S;
      if (wv < 3) {                 // key base q0+4g4 multiple of 4 -> aligned b64
        *(s16x4*)(row + q0 + 4 * g4) = pack4(acc[u9][0], acc[u9][1], acc[u9][2], acc[u9][3]);
      } else {                      // q0=33: odd base, scalar writes
#pragma unroll
        for (int r = 0; r < 4; ++r) row[q0 + 4 * g4 + r] = f2bf_f(acc[u9][r]);
      }
    }
  }

  // ---- K + Q projection (own token tile) ----
  {
    f32x4 kacc[6] = {{0,0,0,0},{0,0,0,0},{0,0,0,0},{0,0,0,0},{0,0,0,0},{0,0,0,0}};
    f32x4 qacc[6] = {{0,0,0,0},{0,0,0,0},{0,0,0,0},{0,0,0,0},{0,0,0,0},{0,0,0,0}};
#pragma unroll
    for (int kf = 0; kf < 3; ++kf) {
      bf16x8 wkf[6], wqf[6];
#pragma unroll
      for (int oct = 0; oct < 6; ++oct) {
        wkf[oct] = *(const bf16x8*)(wsT + 9216 + (oct * 16 + c16) * 96 + kf * 32 + g4 * 8);
        wqf[oct] = *(const bf16x8*)(wsT +        (oct * 16 + c16) * 96 + kf * 32 + g4 * 8);
      }
      __builtin_amdgcn_s_setprio(1);
#pragma unroll
      for (int oct = 0; oct < 6; ++oct) {
        kacc[oct] = __builtin_amdgcn_mfma_f32_16x16x32_bf16(vf[kf], wkf[oct], kacc[oct], 0, 0, 0);
        qacc[oct] = __builtin_amdgcn_mfma_f32_16x16x32_bf16(xf[kf], wqf[oct], qacc[oct], 0, 0, 0);
      }
      __builtin_amdgcn_s_setprio(0);
    }
    const float scale = 0.2550348742f;  // 32^-0.5 * log2(e)
#pragma unroll
    for (int oct = 0; oct < 6; ++oct) {
      float kb = bkvv[oct], qb = bqv[oct];
#pragma unroll
      for (int r = 0; r < 4; ++r)
        Ks[(q0 + 4 * g4 + r) * KS_S + oct * 16 + c16] = f2bf_f(kacc[oct][r] + kb);
#pragma unroll
      for (int r = 0; r < 4; ++r)
        bnc[(4 * g4 + r) * BN_S + oct * 16 + c16] = f2bf_f((qacc[oct][r] + qb) * scale);
    }
  }
  __syncthreads();   // the only block barrier

  // ---- attention ----
  const int q = q0 + c16;
  s16x8 vmask;
#pragma unroll
  for (int j = 0; j < 8; ++j)
    vmask[j] = (short)(((32 + g4 * 8 + j) < 49) ? 0xFFFF : 0x0000);

  // bias rows + output bias (independent early loads)
  f32x4 b0v[4], b1v[4], b2v[4];
  {
    const float* br0 = biasf + q * 64 + 4 * g4;
    const float* br1 = biasf + (49 + q) * 64 + 4 * g4;
    const float* br2 = biasf + (98 + q) * 64 + 4 * g4;
#pragma unroll
    for (int kt = 0; kt < 4; ++kt) {
      b0v[kt] = *(const f32x4*)(br0 + 16 * kt);
      b1v[kt] = *(const f32x4*)(br1 + 16 * kt);
      b2v[kt] = *(const f32x4*)(br2 + 16 * kt);
    }
  }
  float btotv[6];
#pragma unroll
  for (int oct = 0; oct < 6; ++oct) btotv[oct] = btot[oct * 16 + c16];

  // Q fragments from private bounce (reads issued before any P overwrite)
  bf16x8 qf0 = *(const bf16x8*)(bnc + c16 * BN_S + g4 * 8);
  bf16x8 qf1 = *(const bf16x8*)(bnc + c16 * BN_S + 32 + g4 * 8);
  bf16x8 qf2 = *(const bf16x8*)(bnc + c16 * BN_S + 64 + g4 * 8);

  auto softmax_pw = [&](const f32x4* s, const f32x4* bv, int pcol) {
    float vals[16];
#pragma unroll
    for (int kt = 0; kt < 4; ++kt)
#pragma unroll
      for (int r = 0; r < 4; ++r) {
        int key = 16 * kt + 4 * g4 + r;
        vals[kt * 4 + r] = (kt < 3 || key < 49) ? (s[kt][r] + bv[kt][r]) : -1e30f;
      }
    float m8[8];
#pragma unroll
    for (int j = 0; j < 8; ++j) m8[j] = fmaxf(vals[j], vals[j + 8]);
    float ma = fmaxf(m8[0], m8[4]), mb = fmaxf(m8[1], m8[5]);
    float mc = fmaxf(m8[2], m8[6]), md = fmaxf(m8[3], m8[7]);
    float mx = fmaxf(fmaxf(ma, mb), fmaxf(mc, md));
    mx = fmaxf(mx, __shfl_xor(mx, 16, 64));
    mx = fmaxf(mx, __shfl_xor(mx, 32, 64));
    float e[16];
#pragma unroll
    for (int j = 0; j < 16; ++j) e[j] = EXP2F(vals[j] - mx);
    float s8[8];
#pragma unroll
    for (int j = 0; j < 8; ++j) s8[j] = e[j] + e[j + 8];
    float sa = s8[0] + s8[4], sb = s8[1] + s8[5], sc = s8[2] + s8[6], sd = s8[3] + s8[7];
    float sum = (sa + sb) + (sc + sd);
    sum += __shfl_xor(sum, 16, 64);
    sum += __shfl_xor(sum, 32, 64);
    float rinv = 1.0f / sum;
#pragma unroll
    for (int kt = 0; kt < 4; ++kt)
      *(s16x4*)(bnc + c16 * BN_S + pcol + 16 * kt + 4 * g4) =
          pack4(e[kt*4] * rinv, e[kt*4+1] * rinv, e[kt*4+2] * rinv, e[kt*4+3] * rinv);
  };

  // QK^T all heads: A = K key-tiles (shared LDS), B = Q -> C[key][query]
  f32x4 s0[4], s1[4], s2[4];
  {
    bf16x8 ak0[4], ak1[4], ak2[4];
#pragma unroll
    for (int kt = 0; kt < 4; ++kt) {
      ak0[kt] = *(const bf16x8*)(Ks + (16 * kt + c16) * KS_S + g4 * 8);
      ak1[kt] = *(const bf16x8*)(Ks + (16 * kt + c16) * KS_S + 32 + g4 * 8);
      ak2[kt] = *(const bf16x8*)(Ks + (16 * kt + c16) * KS_S + 64 + g4 * 8);
    }
    __builtin_amdgcn_s_setprio(1);
#pragma unroll
    for (int kt = 0; kt < 4; ++kt) {
      s0[kt] = __builtin_amdgcn_mfma_f32_16x16x32_bf16(ak0[kt], qf0, (f32x4){0,0,0,0}, 0, 0, 0);
      s1[kt] = __builtin_amdgcn_mfma_f32_16x16x32_bf16(ak1[kt], qf1, (f32x4){0,0,0,0}, 0, 0, 0);
      s2[kt] = __builtin_amdgcn_mfma_f32_16x16x32_bf16(ak2[kt], qf2, (f32x4){0,0,0,0}, 0, 0, 0);
    }
    __builtin_amdgcn_s_setprio(0);
  }

  // all three softmaxes + P writes, then ONE drain
  softmax_pw(s0, b0v, 0);     // P0 -> 0..63   (Q cols 0..63 dead: qf reads issued)
  softmax_pw(s1, b1v, 64);    // P1 -> 64..127 (Q cols 64..95 dead)
  softmax_pw(s2, b2v, 128);   // P2 -> 128..191 (fresh)
  DRAIN();

  // PV': A = P_h[q][key], B = V'^T[h*96+oc][key] -> C[q][oc], summed over heads
  bf16x8 ap[3][2];
#pragma unroll
  for (int h = 0; h < 3; ++h) {
    ap[h][0] = *(const bf16x8*)(bnc + c16 * BN_S + h * 64 + g4 * 8);
    ap[h][1] = *(const bf16x8*)(bnc + c16 * BN_S + h * 64 + 32 + g4 * 8);
  }
  f32x4 facc[6] = {{0,0,0,0},{0,0,0,0},{0,0,0,0},{0,0,0,0},{0,0,0,0},{0,0,0,0}};
#pragma unroll
  for (int h = 0; h < 3; ++h) {
#pragma unroll
    for (int oct = 0; oct < 6; ++oct) {
      const unsigned short* row = VPT + (h * 96 + oct * 16 + c16) * VT_S;
      bf16x8 bv0 = *(const bf16x8*)(row + g4 * 8);
      s16x8 t = *(const s16x8*)(row + 32 + g4 * 8);
      t &= vmask;
      facc[oct] = __builtin_amdgcn_mfma_f32_16x16x32_bf16(ap[h][0], bv0, facc[oct], 0, 0, 0);
      facc[oct] = __builtin_amdgcn_mfma_f32_16x16x32_bf16(ap[h][1], __builtin_bit_cast(bf16x8, t), facc[oct], 0, 0, 0);
    }
  }

  // ---- store: lane holds out[token=q0+4g4+r][oc=oct*16+c16] ----
  {
    float* obase = outg + (size_t)win * (NTOK * CDIM);
#pragma unroll
    for (int oct = 0; oct < 6; ++oct) {
      float bt = btotv[oct];
#pragma unroll
      for (int r = 0; r < 4; ++r) {
        if (wv < 3 || (4 * g4 + r) == 15) {   // tile 3 stores only token 48
          int tok = q0 + 4 * g4 + r;
          obase[tok * 96 + oct * 16 + c16] = facc[oct][r] + bt;
        }
      }
    }
  }
}

extern "C" void kernel_launch(void* const* d_in, const int* in_sizes, int n_in,
                              void* d_out, int out_size, void* d_ws, size_t ws_size,
                              hipStream_t stream) {
  const float* x     = (const float*)d_in[0];
  const float* v     = (const float*)d_in[1];
  const float* wq    = (const float*)d_in[2];
  const float* bq    = (const float*)d_in[3];
  const float* wkv   = (const float*)d_in[4];
  const float* bkv   = (const float*)d_in[5];
  const float* wproj = (const float*)d_in[6];
  const float* bproj = (const float*)d_in[7];
  const float* rpb   = (const float*)d_in[8];
  const int*   relidx= (const int*)d_in[9];
  float* out = (float*)d_out;
  unsigned short* wsT = (unsigned short*)d_ws;
  float* biasf = (float*)((char*)d_ws + 92160);
  float* btot  = (float*)((char*)d_ws + 129792);
  int nwin = in_sizes[0] / (NTOK * CDIM);   // 8192

  hipLaunchKernelGGL(prep, dim3(218), dim3(256), 0, stream,
                     wq, wkv, wproj, rpb, relidx, bkv, bproj, wsT, biasf, btot);
  hipLaunchKernelGGL(attn_fused, dim3(nwin), dim3(256), 0, stream,
                     x, v, bq, bkv, wsT, biasf, btot, out);
}